// Round 13
// baseline (283.253 us; speedup 1.0000x reference)
//
#include <hip/hip_runtime.h>

// PGA G(3,0,1) GeometricBilinear — R12 "flipped" kernel (R13 resubmit; R12
// bench died on container infra).
// P=16384, CIN=64, 2H=256, H=128, COUT=64, 16 blades.
//
// R11 post-mortem: wave=channel-group gives ZERO weight reuse across waves
// (disjoint rows) -> 1.2GB L2 traffic + every load latency-exposed (compiler
// won't deep-pipeline; VGPR=112). R12 flips: wave=POSITION-tile, channels
// looped -> all 4 waves load IDENTICAL weight fragments (L1-shared), weights
// pre-swizzled per-fragment (w1f/w2f: 512 bf16 = lane-major, one coalesced
// 16B/lane load). MFMA operands swap roles: A = X (M=pos rows), B = W
// (N=ch cols); D: lane ln = ch, lh*4+r = pos (dtype-independent C/D layout).
// Phase1 products stay per-lane elementwise (verified R10/R11 tables).
// out2 -> global bounce [pos][e2 8][cc 128][s 2] bf16 (64MB in d_ws);
// phase2 re-stages 16-pos groups to LDS, j2-GEMMs at K=256 (even j2
// zero-padded in w2f), coalesced 64B-line out stores.
// Replay-stale-L1 on out2 is safe: deterministic -> identical bytes.

namespace {

constexpr int popc4(int v){int c=0;while(v){c+=v&1;v>>=1;}return c;}
constexpr float sgnf(int a,int b){int s=0;a>>=1;while(a){s+=popc4(a&b);a>>=1;}return (s&1)?-1.f:1.f;}

struct Tabs { float gp[16][16]; float jn[16][16]; };
constexpr Tabs mk(){
    Tabs t{};
    for(int a=0;a<16;a++)for(int b=0;b<16;b++){
        t.gp[a][b] = (a&b&1) ? 0.f : sgnf(a,b);
        if((a|b)==15){
            const int k = a&b;
            t.jn[a][b] = sgnf(a,15^a)*sgnf(b,15^b)*sgnf(15^a,15^b)*sgnf(k,15^k);
        } else t.jn[a][b] = 0.f;
    }
    return t;
}
constexpr Tabs TB = mk();
constexpr int GE[8] = {0,1,1,2,1,2,2,3};  // f32 fallback

// ---- R12 fragment-packed weights ----
// w1f: 16 f-groups x 48 frags x 512 bf16 (lane-major: lane l holds 8 elems)
constexpr int FOFF(int j){ return (j>>1)*6 + ((j&1)?2:0); } // frag base within 48
constexpr int W1F_ELEMS = 16*48*512;    // 393216
// w2f: 4 og x 16 j2 x 8 kf x 512 (K=256 over k'=(cc,s); even j2 s=1 zeroed)
constexpr int W2F_ELEMS = 4*16*8*512;   // 262144
constexpr long O2_BYTES = (long)16384*4096;  // out2 bounce, bf16 [pos][e2][cc][s]

// ---- R11 row-packed weights (middle fallback) ----
constexpr int BASE1(int j){ return (j>>1)*192 + ((j&1)?64:0); }
constexpr int BASE2(int j){ return (j>>1)*384 + ((j&1)?128:0); }
constexpr int W1C_ELEMS = 256*1536;
constexpr int W2C_ELEMS = 64*3072;
constexpr int X1_STRIDE = 272;
constexpr int X2_STRIDE = 544;
constexpr int EP_STRIDE = 4112;
constexpr int X1_BYTES  = 128*X1_STRIDE;
constexpr int X2_BYTES  = 128*X2_STRIDE;

typedef short bf16x8 __attribute__((ext_vector_type(8)));
typedef float f32x4  __attribute__((ext_vector_type(4)));

__device__ inline unsigned short f2bf(float f){
    unsigned int u = __float_as_uint(f);
    u = u + 0x7fffu + ((u >> 16) & 1u);
    return (unsigned short)(u >> 16);
}
__device__ inline unsigned pack2(float a, float b){
    return (unsigned)f2bf(a) | ((unsigned)f2bf(b) << 16);
}

} // namespace

// ================= R12 prep: fragment-swizzled weight pack ===================
__global__ void prep_w2(const float* __restrict__ w1, const float* __restrict__ w2,
                        unsigned short* __restrict__ w1f, unsigned short* __restrict__ w2f)
{
    int idx = blockIdx.x * 256 + threadIdx.x;
    if (idx < W1F_ELEMS) {
        const int fid = idx >> 9, r = idx & 511, l = r >> 3, m = r & 7;
        const int f = fid / 48, rem = fid - f*48;
        const int e = rem / 6, r6 = rem - e*6;
        const int odd = (r6 >= 2) ? 1 : 0;
        const int j = 2*e + odd, kf = odd ? r6 - 2 : r6;
        const int k = kf*32 + (l >> 4)*8 + m;
        const int ch = f*16 + (l & 15);
        const int g = popc4(j);
        float v;
        if (!odd) v = w1[(ch*64 + k)*9 + g];
        else      v = (k < 64) ? w1[(ch*64 + k)*9 + g + 4]
                               : w1[(ch*64 + (k - 64))*9 + g];
        w1f[idx] = f2bf(v);
    } else {
        idx -= W1F_ELEMS;
        if (idx < W2F_ELEMS) {
            const int fid = idx >> 9, r = idx & 511, l = r >> 3, m = r & 7;
            const int og = fid >> 7, rem = fid & 127;
            const int j2 = rem >> 3, kf = rem & 7;
            const int kp = kf*32 + (l >> 4)*8 + m;
            const int cc = kp >> 1, s = kp & 1;
            const int o2 = og*16 + (l & 15);
            const int g = popc4(j2);
            float v;
            if (!(j2 & 1)) v = s ? 0.f : w2[(o2*128 + cc)*9 + g];
            else           v = s ? w2[(o2*128 + cc)*9 + g]
                                 : w2[(o2*128 + cc)*9 + g + 4];
            w2f[idx] = f2bf(v);
        }
    }
}

// ================= R12 main kernel: 256 blocks x 256 thr (4 waves) ===========
__global__ __launch_bounds__(256, 1) void gb2(
    const float* __restrict__ x, const float* __restrict__ ref,
    const float* __restrict__ b1, const float* __restrict__ b2,
    const unsigned short* __restrict__ w1f, const unsigned short* __restrict__ w2f,
    unsigned short* __restrict__ o2buf, float* __restrict__ out)
{
    // X1: [e 8][pos 64] rows of 272B (k = s*64+i, byte s*128+i*2). 139264 B.
    // phase2 reuse: [posl 16] rows of 4112B.
    __shared__ __attribute__((aligned(16))) char LDS[139264];
    __shared__ float lref[64];

    const int t  = threadIdx.x;
    const int w  = t >> 6;         // wave 0..3 = pos-tile (phase1) / og (phase2)
    const int l  = t & 63;
    const int ln = l & 15;
    const int lh = l >> 4;
    const int p0 = blockIdx.x * 64;
    const int pw = w * 16;         // local pos-tile base

    // ---- stage X1 (64 pos x 1KB fp32 -> bf16) ----
    #pragma unroll
    for (int it = 0; it < 8; ++it) {
        const int id = t + it*256;            // 2048 tasks = 64 pos x 32 i-pairs
        const int pos = id >> 5, ip = (id & 31)*2;
        const float* gs = x + (long)(p0 + pos)*1024 + ip*16;
        float4 v[8];
        #pragma unroll
        for (int a = 0; a < 8; ++a) v[a] = *(const float4*)(gs + a*4);
        char* base = LDS + pos*272 + ip*2;
        #pragma unroll
        for (int b = 0; b < 16; ++b) {
            const int e = b >> 1, s = b & 1;
            *(unsigned*)(base + e*17408 + s*128) =
                pack2(((const float*)&v[b>>2])[b&3], ((const float*)&v[4 + (b>>2)])[b&3]);
        }
    }
    if (t < 64) lref[t] = ref[(long)(p0 + t)*16 + 15];
    __syncthreads();

    // ---- phase 1: loop 8 channel-groups; all waves share weight addresses ----
    #pragma unroll 1
    for (int cg = 0; cg < 8; ++cg) {
        const int stc = cg >> 2, grpc = cg & 3;
        const int f0 = stc ? grpc + 8 : grpc;
        const unsigned short* wL = w1f + (f0    )*48*512 + l*8;
        const unsigned short* wR = w1f + (f0 + 4)*48*512 + l*8;

        f32x4 left[16];
        #pragma unroll
        for (int j = 0; j < 16; ++j) left[j] = (f32x4)0.f;
        #pragma unroll
        for (int j = 0; j < 16; ++j) {
            const int e = j >> 1, nkf = (j & 1) ? 4 : 2;
            #pragma unroll
            for (int kf = 0; kf < nkf; ++kf) {
                const bf16x8 a = *(const bf16x8*)(LDS + e*17408 + (pw + ln)*272 + kf*64 + lh*16);
                const bf16x8 b = *(const bf16x8*)(wL + (FOFF(j) + kf)*512);
                left[j] = __builtin_amdgcn_mfma_f32_16x16x32_bf16(a, b, left[j], 0, 0, 0);
            }
        }
        {
            const float bv = b1[f0*16 + ln];
            #pragma unroll
            for (int r = 0; r < 4; ++r) left[0][r] += bv;
        }

        f32x4 prod[16];
        #pragma unroll
        for (int j = 0; j < 16; ++j) prod[j] = (f32x4)0.f;

        #pragma unroll
        for (int j = 0; j < 16; ++j) {
            const int e = j >> 1, nkf = (j & 1) ? 4 : 2;
            f32x4 right = (f32x4)0.f;
            #pragma unroll
            for (int kf = 0; kf < nkf; ++kf) {
                const bf16x8 a = *(const bf16x8*)(LDS + e*17408 + (pw + ln)*272 + kf*64 + lh*16);
                const bf16x8 b = *(const bf16x8*)(wR + (FOFF(j) + kf)*512);
                right = __builtin_amdgcn_mfma_f32_16x16x32_bf16(a, b, right, 0, 0, 0);
            }
            if (j == 0) {
                const float bv = b1[(f0 + 4)*16 + ln];
                #pragma unroll
                for (int r = 0; r < 4; ++r) right[r] += bv;
            }
            if (stc == 0) {
                #pragma unroll
                for (int A = 0; A < 16; ++A) {
                    if (TB.gp[A][j] > 0.f)      prod[A ^ j] += left[A] * right;
                    else if (TB.gp[A][j] < 0.f) prod[A ^ j] -= left[A] * right;
                }
            } else {
                #pragma unroll
                for (int A = 0; A < 16; ++A) {
                    if (TB.jn[A][j] > 0.f)      prod[A & j] += left[A] * right;
                    else if (TB.jn[A][j] < 0.f) prod[A & j] -= left[A] * right;
                }
            }
        }
        if (stc == 1) {
            #pragma unroll
            for (int r = 0; r < 4; ++r) {
                const float rv = lref[pw + lh*4 + r];
                #pragma unroll
                for (int j = 0; j < 16; ++j) prod[j][r] *= rv;
            }
        }

        // store out2: [pos][e2][cc][s] bf16; cc = product channel
        const int cc = stc*64 + grpc*16 + ln;
        #pragma unroll
        for (int r = 0; r < 4; ++r) {
            char* gd = (char*)o2buf + (long)(p0 + pw + lh*4 + r)*4096 + cc*4;
            #pragma unroll
            for (int e2 = 0; e2 < 8; ++e2)
                *(unsigned*)(gd + e2*512) = pack2(prod[2*e2][r], prod[2*e2+1][r]);
        }
    }
    asm volatile("s_waitcnt vmcnt(0)" ::: "memory");
    __syncthreads();

    // ---- phase 2: 4 pos-groups; wave = o2-group; K=256 per j2 ----
    #pragma unroll 1
    for (int g = 0; g < 4; ++g) {
        __syncthreads();   // prior group's LDS reads complete
        #pragma unroll
        for (int it = 0; it < 16; ++it) {
            const int id = t + it*256;            // 4096 x 16B chunks
            const int posl = id >> 8, off = (id & 255)*16;
            *(float4*)(LDS + posl*4112 + off) =
                *(const float4*)((const char*)o2buf + (long)(p0 + g*16 + posl)*4096 + off);
        }
        __syncthreads();

        f32x4 acc[16];
        #pragma unroll
        for (int j2 = 0; j2 < 16; ++j2) acc[j2] = (f32x4)0.f;
        #pragma unroll
        for (int j2 = 0; j2 < 16; ++j2) {
            const int e2 = j2 >> 1;
            #pragma unroll
            for (int kf = 0; kf < 8; ++kf) {
                const bf16x8 a = *(const bf16x8*)(LDS + ln*4112 + e2*512 + kf*64 + lh*16);
                const bf16x8 b = *(const bf16x8*)(w2f + (w*128 + j2*8 + kf)*512 + l*8);
                acc[j2] = __builtin_amdgcn_mfma_f32_16x16x32_bf16(a, b, acc[j2], 0, 0, 0);
            }
        }
        {
            const float bv = b2[w*16 + ln];
            #pragma unroll
            for (int r = 0; r < 4; ++r) acc[0][r] += bv;
        }
        #pragma unroll
        for (int r = 0; r < 4; ++r) {
            float* gd = out + (long)(p0 + g*16 + lh*4 + r)*1024 + (w*16 + ln)*16;
            *(float4*)(gd)      = make_float4(acc[0][r],  acc[1][r],  acc[2][r],  acc[3][r]);
            *(float4*)(gd + 4)  = make_float4(acc[4][r],  acc[5][r],  acc[6][r],  acc[7][r]);
            *(float4*)(gd + 8)  = make_float4(acc[8][r],  acc[9][r],  acc[10][r], acc[11][r]);
            *(float4*)(gd + 12) = make_float4(acc[12][r], acc[13][r], acc[14][r], acc[15][r]);
        }
    }
}

// ================= R11 middle fallback (verified, verbatim) ==================
__global__ void prep_w_c(const float* __restrict__ w1, const float* __restrict__ w2,
                         unsigned short* __restrict__ w1c, unsigned short* __restrict__ w2c)
{
    int idx = blockIdx.x * 256 + threadIdx.x;
    if (idx < W1C_ELEMS) {
        const int o = idx / 1536, r = idx - o*1536;
        const int p = r / 192, q = r - p*192;
        float v;
        if (q < 64) {
            v = w1[(o*64 + q)*9 + popc4(2*p)];
        } else {
            const int j = 2*p + 1, k = q - 64, g = popc4(j);
            v = (k < 64) ? w1[(o*64 + k)*9 + g + 4]
                         : w1[(o*64 + (k - 64))*9 + g];
        }
        w1c[idx] = f2bf(v);
    } else {
        idx -= W1C_ELEMS;
        if (idx < W2C_ELEMS) {
            const int o = idx / 3072, r = idx - o*3072;
            const int p = r / 384, q = r - p*384;
            float v;
            if (q < 128) {
                v = w2[(o*128 + q)*9 + popc4(2*p)];
            } else {
                const int j = 2*p + 1, k = q - 128, g = popc4(j);
                v = (k < 128) ? w2[(o*128 + k)*9 + g + 4]
                              : w2[(o*128 + (k - 128))*9 + g];
            }
            w2c[idx] = f2bf(v);
        }
    }
}

__global__ __launch_bounds__(512, 2) void gb_mfma_c(
    const float* __restrict__ x, const float* __restrict__ ref,
    const float* __restrict__ b1, const float* __restrict__ b2,
    const unsigned short* __restrict__ w1c, const unsigned short* __restrict__ w2c,
    float* __restrict__ out)
{
    __shared__ __attribute__((aligned(16))) char X1[X1_BYTES];
    __shared__ __attribute__((aligned(16))) char X2[X2_BYTES];
    __shared__ float lref[16];

    const int t   = threadIdx.x;
    const int bid = blockIdx.x;
    const int w   = t >> 6;
    const int l   = t & 63;
    const int ln  = l & 15;
    const int lh  = l >> 4;
    const int p0  = bid * 16;

    const int st  = w >> 2;
    const int grp = w & 3;
    const int f0  = (st == 0) ? grp : grp + 8;

    const unsigned short* pA = w1c + (f0*16 + ln)*1536;
    const unsigned short* pB = w1c + ((f0+4)*16 + ln)*1536;
    const unsigned short* pC = w2c + (grp*16 + ln)*3072 + 1536;
    const int vX1 = ln*X1_STRIDE + lh*16;
    const int vX2 = ln*X2_STRIDE + lh*16;
    const int vX2w = ln*X2_STRIDE + w*32 + lh*8;
    const int vEp  = ln*EP_STRIDE + grp*1024 + lh*256 + st*32;

    {
        const int spos = t >> 5;
        const int si0  = (t & 31) * 2;
        const float* gsrc = x + ((long)(p0 + spos))*1024 + si0*16;
        float4 v[8];
        #pragma unroll
        for (int a = 0; a < 8; ++a) v[a] = *(const float4*)(gsrc + a*4);
        char* base = X1 + spos*X1_STRIDE + si0*2;
        #pragma unroll
        for (int b = 0; b < 16; ++b) {
            const int e = b >> 1, s = b & 1;
            const float va = ((const float*)&v[b>>2])[b&3];
            const float vb = ((const float*)&v[4 + (b>>2)])[b&3];
            *(unsigned*)(base + e*16*X1_STRIDE + s*128) = pack2(va, vb);
        }
        if (t < 16) lref[t] = ref[((long)(p0 + t))*16 + 15];
    }
    __syncthreads();

    f32x4 left[16];
    #pragma unroll
    for (int j = 0; j < 16; ++j) left[j] = (f32x4)0.f;
    #pragma unroll
    for (int j = 0; j < 16; ++j) {
        const int e = j >> 1, nkf = (j & 1) ? 4 : 2;
        #pragma unroll
        for (int kf = 0; kf < nkf; ++kf) {
            const bf16x8 a  = *(const bf16x8*)(pA + BASE1(j) + kf*32 + lh*8);
            const bf16x8 bx = *(const bf16x8*)(X1 + vX1 + e*16*X1_STRIDE + kf*64);
            left[j] = __builtin_amdgcn_mfma_f32_16x16x32_bf16(a, bx, left[j], 0, 0, 0);
        }
    }
    #pragma unroll
    for (int r = 0; r < 4; ++r) left[0][r] += b1[f0*16 + lh*4 + r];

    f32x4 prod[16];
    #pragma unroll
    for (int j = 0; j < 16; ++j) prod[j] = (f32x4)0.f;
    #pragma unroll
    for (int j = 0; j < 16; ++j) {
        const int e = j >> 1, nkf = (j & 1) ? 4 : 2;
        f32x4 right = (f32x4)0.f;
        #pragma unroll
        for (int kf = 0; kf < nkf; ++kf) {
            const bf16x8 a  = *(const bf16x8*)(pB + BASE1(j) + kf*32 + lh*8);
            const bf16x8 bx = *(const bf16x8*)(X1 + vX1 + e*16*X1_STRIDE + kf*64);
            right = __builtin_amdgcn_mfma_f32_16x16x32_bf16(a, bx, right, 0, 0, 0);
        }
        if (j == 0) {
            #pragma unroll
            for (int r = 0; r < 4; ++r) right[r] += b1[(f0+4)*16 + lh*4 + r];
        }
        if (st == 0) {
            #pragma unroll
            for (int A = 0; A < 16; ++A) {
                if (TB.gp[A][j] > 0.f)      prod[A ^ j] += left[A] * right;
                else if (TB.gp[A][j] < 0.f) prod[A ^ j] -= left[A] * right;
            }
        } else {
            #pragma unroll
            for (int A = 0; A < 16; ++A) {
                if (TB.jn[A][j] > 0.f)      prod[A & j] += left[A] * right;
                else if (TB.jn[A][j] < 0.f) prod[A & j] -= left[A] * right;
            }
        }
    }
    if (st == 1) {
        const float rv = lref[ln];
        #pragma unroll
        for (int j = 0; j < 16; ++j) prod[j] *= rv;
    }

    #pragma unroll
    for (int e2 = 0; e2 < 8; ++e2)
        #pragma unroll
        for (int s = 0; s < 2; ++s)
            #pragma unroll
            for (int rp = 0; rp < 4; rp += 2)
                *(unsigned*)(X2 + vX2w + e2*16*X2_STRIDE + s*256 + rp*2) =
                    pack2(prod[2*e2 + s][rp], prod[2*e2 + s][rp + 1]);
    __syncthreads();

    f32x4 acc2[8];
    #pragma unroll
    for (int jj = 0; jj < 8; ++jj) acc2[jj] = (f32x4)0.f;
    #pragma unroll
    for (int jj = 0; jj < 8; ++jj) {
        const int j2 = st*8 + jj;
        const int e2 = j2 >> 1, nkf = (j2 & 1) ? 8 : 4;
        #pragma unroll
        for (int kf = 0; kf < nkf; ++kf) {
            const bf16x8 a  = *(const bf16x8*)(pC + (BASE2(j2) - 1536) + kf*32 + lh*8);
            const bf16x8 bx = *(const bf16x8*)(X2 + vX2 + e2*16*X2_STRIDE + kf*64);
            acc2[jj] = __builtin_amdgcn_mfma_f32_16x16x32_bf16(a, bx, acc2[jj], 0, 0, 0);
        }
    }
    if (st == 0) {
        #pragma unroll
        for (int r = 0; r < 4; ++r) acc2[0][r] += b2[grp*16 + lh*4 + r];
    }
    __syncthreads();

    #pragma unroll
    for (int r = 0; r < 4; ++r) {
        *(float4*)(X2 + vEp + r*64)      = make_float4(acc2[0][r], acc2[1][r], acc2[2][r], acc2[3][r]);
        *(float4*)(X2 + vEp + r*64 + 16) = make_float4(acc2[4][r], acc2[5][r], acc2[6][r], acc2[7][r]);
    }
    __syncthreads();
    {
        const int pr = t >> 8;
        const int off = t & 255;
        const char* rbase = X2 + pr*EP_STRIDE + off*16;
        float* gbase = out + ((long)(p0 + pr))*1024 + off*4;
        #pragma unroll
        for (int it = 0; it < 8; ++it)
            *(float4*)(gbase + (long)it*2048) = *(const float4*)(rbase + it*2*EP_STRIDE);
    }
}

// ================= fp32 last-resort fallback (verified R3) ===================
__global__ __launch_bounds__(256, 1) void gb_fused_f32(
    const float* __restrict__ x, const float* __restrict__ ref,
    const float* __restrict__ w1, const float* __restrict__ b1,
    const float* __restrict__ w2, const float* __restrict__ b2,
    float* __restrict__ out)
{
    __shared__ float lds[16384];
    __shared__ float lrefs[8];
    const int t = threadIdx.x;
    const int p0 = blockIdx.x * 8;
    {
        const float4* xg = reinterpret_cast<const float4*>(x) + (size_t)p0 * 256;
        float4* xl = reinterpret_cast<float4*>(lds);
        #pragma unroll
        for (int r = 0; r < 8; ++r) xl[r*256 + t] = xg[r*256 + t];
        if (t < 8) lrefs[t] = ref[(p0 + t)*16 + 15];
    }
    __syncthreads();
    const int c    = t & 127;
    const int half = t >> 7;
    const int ca   = (c < 64) ? c : (c + 64);
    const int cb   = ca + 64;
    float acc[4][2][16];
    #pragma unroll
    for (int q = 0; q < 4; ++q)
        #pragma unroll
        for (int s = 0; s < 2; ++s)
            #pragma unroll
            for (int j = 0; j < 16; ++j) acc[q][s][j] = 0.f;
    for (int i = 0; i < 64; ++i) {
        float wa[9], wb[9];
        #pragma unroll
        for (int r = 0; r < 9; ++r) { wa[r] = w1[(ca*64+i)*9 + r]; wb[r] = w1[(cb*64+i)*9 + r]; }
        #pragma unroll
        for (int q = 0; q < 4; ++q) {
            const float* xv = lds + (half*4 + q)*1024 + i*16;
            float xr[16];
            #pragma unroll
            for (int j4 = 0; j4 < 4; ++j4) {
                const float4 v = *reinterpret_cast<const float4*>(xv + 4*j4);
                xr[4*j4+0]=v.x; xr[4*j4+1]=v.y; xr[4*j4+2]=v.z; xr[4*j4+3]=v.w;
            }
            #pragma unroll
            for (int e = 0; e < 8; ++e) {
                const int ge = GE[e];
                const float xe = xr[2*e], xo = xr[2*e+1];
                acc[q][0][2*e]   += wa[ge]   * xe;
                acc[q][0][2*e+1] += wa[ge+1] * xo;
                acc[q][0][2*e+1] += wa[ge+5] * xe;
                acc[q][1][2*e]   += wb[ge]   * xe;
                acc[q][1][2*e+1] += wb[ge+1] * xo;
                acc[q][1][2*e+1] += wb[ge+5] * xe;
            }
        }
    }
    {
        const float ba = b1[ca], bb = b1[cb];
        #pragma unroll
        for (int q = 0; q < 4; ++q) { acc[q][0][0] += ba; acc[q][1][0] += bb; }
    }
    __syncthreads();
    #pragma unroll
    for (int q = 0; q < 4; ++q) {
        float prod[16];
        #pragma unroll
        for (int j = 0; j < 16; ++j) prod[j] = 0.f;
        if (c < 64) {
            #pragma unroll
            for (int A = 0; A < 16; ++A)
                #pragma unroll
                for (int B = 0; B < 16; ++B)
                    if (TB.gp[A][B] != 0.f)
                        prod[A ^ B] += TB.gp[A][B] * acc[q][0][A] * acc[q][1][B];
        } else {
            #pragma unroll
            for (int A = 0; A < 16; ++A)
                #pragma unroll
                for (int B = 0; B < 16; ++B)
                    if (TB.jn[A][B] != 0.f)
                        prod[A & B] += TB.jn[A][B] * acc[q][0][A] * acc[q][1][B];
            const float rp = lrefs[half*4 + q];
            #pragma unroll
            for (int j = 0; j < 16; ++j) prod[j] *= rp;
        }
        const int pos = half*4 + q;
        #pragma unroll
        for (int j4 = 0; j4 < 4; ++j4)
            *reinterpret_cast<float4*>(&lds[(pos*4 + j4)*512 + c*4]) =
                make_float4(prod[4*j4], prod[4*j4+1], prod[4*j4+2], prod[4*j4+3]);
    }
    __syncthreads();
    const int o    = t & 63;
    const int slot = t >> 6;
    float oacc[2][16];
    #pragma unroll
    for (int e2 = 0; e2 < 2; ++e2)
        #pragma unroll
        for (int j = 0; j < 16; ++j) oacc[e2][j] = 0.f;
    for (int i = 0; i < 128; ++i) {
        float wv[9];
        #pragma unroll
        for (int r = 0; r < 9; ++r) wv[r] = w2[(o*128+i)*9 + r];
        #pragma unroll
        for (int e2 = 0; e2 < 2; ++e2) {
            const int pos = slot*2 + e2;
            float xr[16];
            #pragma unroll
            for (int j4 = 0; j4 < 4; ++j4) {
                const float4 v = *reinterpret_cast<const float4*>(&lds[(pos*4 + j4)*512 + i*4]);
                xr[4*j4+0]=v.x; xr[4*j4+1]=v.y; xr[4*j4+2]=v.z; xr[4*j4+3]=v.w;
            }
            #pragma unroll
            for (int e = 0; e < 8; ++e) {
                const int ge = GE[e];
                oacc[e2][2*e]   += wv[ge]   * xr[2*e];
                oacc[e2][2*e+1] += wv[ge+1] * xr[2*e+1];
                oacc[e2][2*e+1] += wv[ge+5] * xr[2*e];
            }
        }
    }
    {
        const float bo = b2[o];
        #pragma unroll
        for (int e2 = 0; e2 < 2; ++e2) {
            oacc[e2][0] += bo;
            const int pos = p0 + slot*2 + e2;
            float* og = out + (size_t)pos*1024 + o*16;
            #pragma unroll
            for (int j4 = 0; j4 < 4; ++j4)
                *reinterpret_cast<float4*>(og + 4*j4) =
                    make_float4(oacc[e2][4*j4], oacc[e2][4*j4+1],
                                oacc[e2][4*j4+2], oacc[e2][4*j4+3]);
        }
    }
}

extern "C" void kernel_launch(void* const* d_in, const int* in_sizes, int n_in,
                              void* d_out, int out_size, void* d_ws, size_t ws_size,
                              hipStream_t stream)
{
    const float* x  = (const float*)d_in[0];
    const float* rf = (const float*)d_in[1];
    const float* w1 = (const float*)d_in[2];
    const float* b1 = (const float*)d_in[3];
    const float* w2 = (const float*)d_in[4];
    const float* b2 = (const float*)d_in[5];
    float* out = (float*)d_out;

    const size_t needF = (size_t)O2_BYTES + (size_t)(W1F_ELEMS + W2F_ELEMS)*2;
    const size_t needC = (size_t)(W1C_ELEMS + W2C_ELEMS)*2;
    if (ws_size >= needF) {
        unsigned short* o2buf = (unsigned short*)d_ws;
        unsigned short* w1f = (unsigned short*)((char*)d_ws + O2_BYTES);
        unsigned short* w2f = w1f + W1F_ELEMS;
        prep_w2<<<(W1F_ELEMS + W2F_ELEMS)/256, 256, 0, stream>>>(w1, w2, w1f, w2f);
        gb2<<<256, 256, 0, stream>>>(x, rf, b1, b2, w1f, w2f, o2buf, out);
    } else if (ws_size >= needC) {
        unsigned short* w1c = (unsigned short*)d_ws;
        unsigned short* w2c = w1c + W1C_ELEMS;
        prep_w_c<<<(W1C_ELEMS + W2C_ELEMS)/256, 256, 0, stream>>>(w1, w2, w1c, w2c);
        gb_mfma_c<<<1024, 512, 0, stream>>>(x, rf, b1, b2, w1c, w2c, out);
    } else {
        gb_fused_f32<<<2048, 256, 0, stream>>>(x, rf, w1, b1, w2, b2, out);
    }
}

// Round 14
// 206.562 us; speedup vs baseline: 1.3713x; 1.3713x over previous
//
#include <hip/hip_runtime.h>

// PGA G(3,0,1) GeometricBilinear — R14: DMA-staged weights (global_load_lds).
// P=16384, CIN=64, 2H=256, H=128, COUT=64, 16 blades.
//
// Model (R4-R13): weight-load-latency-bound — each MFMA eats a fresh 16B/lane
// weight fragment; compiler won't pipeline those loads (explicit prefetch
// rings got collapsed, VGPR stayed ~120). Fix: weights go global->LDS via
// __builtin_amdgcn_global_load_lds (no VGPR round-trip, latency paid per
// 32KB chunk behind one barrier), LDS->MFMA is compiler-scheduled well.
// Math/wave-mapping verbatim from verified R9/R11: 8 waves = (st,grp) channel
// groups, 16 pos/block, accL/accR[16] in regs, gp/jn product tables, X2
// [row=e2*16+pos][k2=s*128+cc] 544B rows, padded epilogue.
// Weight chunks are LINEAR in global (DMA dest must be linear, m104/m173);
// the bank-conflict swizzle is pre-applied on the GLOBAL side at pack time
// and re-applied on the LDS read (both-sides rule, m201/m231).
// w1s: 24 chunks x 32KB: c=3e+v -> j=2e+(v>0), khalf=(v==2); [ch 256][kk 64]
//   elem = ch*64 + (kk ^ ((ch&7)*8)).
// w2s: 24 chunks x 16KB: d=3e2+v -> j2, khalf; [ch2 64][kk 128]
//   elem = ch2*128 + (kk ^ ((ch2&7)*8)).

namespace {

constexpr int popc4(int v){int c=0;while(v){c+=v&1;v>>=1;}return c;}
constexpr float sgnf(int a,int b){int s=0;a>>=1;while(a){s+=popc4(a&b);a>>=1;}return (s&1)?-1.f:1.f;}

struct Tabs { float gp[16][16]; float jn[16][16]; };
constexpr Tabs mk(){
    Tabs t{};
    for(int a=0;a<16;a++)for(int b=0;b<16;b++){
        t.gp[a][b] = (a&b&1) ? 0.f : sgnf(a,b);
        if((a|b)==15){
            const int k = a&b;
            t.jn[a][b] = sgnf(a,15^a)*sgnf(b,15^b)*sgnf(15^a,15^b)*sgnf(k,15^k);
        } else t.jn[a][b] = 0.f;
    }
    return t;
}
constexpr Tabs TB = mk();
constexpr int GE[8] = {0,1,1,2,1,2,2,3};  // f32 fallback

constexpr int W1S_ELEMS = 24*16384;   // 393216 (24 x 32KB)
constexpr int W2S_ELEMS = 24*8192;    // 196608 (24 x 16KB)

// LDS map (bytes):
//  [0,34816)        X1 (phase1, 272B rows)  -> X2 [0,69632) -> EP [0,65792)
//  [69632,135168)   WB[2] 32KB (phase1 weight dbuf) -> PB[2] 16KB (phase2)
constexpr int X1_STRIDE = 272;
constexpr int X2_STRIDE = 544;
constexpr int EP_STRIDE = 4112;
constexpr int WBOFF = 69632;
constexpr int LDS_BYTES = 135168;

typedef short bf16x8 __attribute__((ext_vector_type(8)));
typedef float f32x4  __attribute__((ext_vector_type(4)));

__device__ inline unsigned short f2bf(float f){
    unsigned int u = __float_as_uint(f);
    u = u + 0x7fffu + ((u >> 16) & 1u);
    return (unsigned short)(u >> 16);
}
__device__ inline unsigned pack2(float a, float b){
    return (unsigned)f2bf(a) | ((unsigned)f2bf(b) << 16);
}
__device__ __forceinline__ void gload16(const void* g, void* l){
    __builtin_amdgcn_global_load_lds(
        (const __attribute__((address_space(1))) void*)g,
        (__attribute__((address_space(3))) void*)l, 16, 0, 0);
}

} // namespace

// ---------------- prep: pack weights into swizzled linear DMA chunks ---------
__global__ void prep_w(const float* __restrict__ w1, const float* __restrict__ w2,
                       unsigned short* __restrict__ w1s, unsigned short* __restrict__ w2s)
{
    int idx = blockIdx.x * 256 + threadIdx.x;
    if (idx < W1S_ELEMS) {
        const int c = idx >> 14, r = idx & 16383;
        const int ch = r >> 6, kswz = r & 63;
        const int kk = kswz ^ ((ch & 7) * 8);
        const int e = c / 3, v = c - 3*e;
        const int j = 2*e + (v ? 1 : 0);
        const int k = ((v == 2) ? 64 : 0) + kk;
        const int g = popc4(j);
        float val;
        if (v == 0)      val = w1[(ch*64 + k)*9 + g];
        else if (k < 64) val = w1[(ch*64 + k)*9 + g + 4];
        else             val = w1[(ch*64 + (k - 64))*9 + g];
        w1s[idx] = f2bf(val);
    } else {
        idx -= W1S_ELEMS;
        if (idx < W2S_ELEMS) {
            const int d = idx >> 13, r = idx & 8191;
            const int ch2 = r >> 7, kswz = r & 127;
            const int kk = kswz ^ ((ch2 & 7) * 8);
            const int e2 = d / 3, v = d - 3*e2;
            const int j2 = 2*e2 + (v ? 1 : 0);
            const int k2 = ((v == 2) ? 128 : 0) + kk;
            const int g = popc4(j2);
            float val;
            if (v == 0)        val = w2[(ch2*128 + k2)*9 + g];
            else if (k2 < 128) val = w2[(ch2*128 + k2)*9 + g + 4];
            else               val = w2[(ch2*128 + (k2 - 128))*9 + g];
            w2s[idx] = f2bf(val);
        }
    }
}

// ---------------- main: 1024 blocks x 512 thr (8 waves, 2/SIMD) --------------
__global__ __launch_bounds__(512, 2) void gb3(
    const float* __restrict__ x, const float* __restrict__ ref,
    const float* __restrict__ b1, const float* __restrict__ b2,
    const unsigned short* __restrict__ w1s, const unsigned short* __restrict__ w2s,
    float* __restrict__ out)
{
    __shared__ __attribute__((aligned(16))) char LDS[LDS_BYTES];
    __shared__ float lref[16];

    const int t   = threadIdx.x;
    const int w   = t >> 6;        // wave 0..7
    const int l   = t & 63;
    const int ln  = l & 15;        // MFMA: position col
    const int lh  = l >> 4;        // MFMA: k-chunk / channel quad
    const int p0  = blockIdx.x * 16;

    const int st  = w >> 2;        // 0 = geo, 1 = join
    const int grp = w & 3;
    const int f0  = (st == 0) ? grp : grp + 8;
    const int chL = f0*16 + ln;
    const int chR = (f0 + 4)*16 + ln;
    const int aLo = chL*128 + ((lh*16) ^ ((chL & 7) << 4));  // kf2 adds ^64 via re-XOR
    const int aRo = chR*128 + ((lh*16) ^ ((chR & 7) << 4));
    const int dmaOff = w*1024 + l*16;   // lane slot within an 8KB round

    // ---- issue DMA of w1 chunk 0 (overlaps X1 staging) ----
    {
        char* ldst = LDS + WBOFF;
        #pragma unroll
        for (int r = 0; r < 4; ++r)
            gload16((const char*)w1s + r*8192 + dmaOff, ldst + r*8192 + w*1024);
    }

    // ---- stage X1: x[p0..p0+15] fp32 -> bf16 [row=e*16+pos][k*2], 272B rows --
    {
        const int spos = t >> 5;
        const int si0  = (t & 31) * 2;
        const float* gsrc = x + ((long)(p0 + spos))*1024 + si0*16;
        float4 v[8];
        #pragma unroll
        for (int a = 0; a < 8; ++a) v[a] = *(const float4*)(gsrc + a*4);
        char* base = LDS + spos*X1_STRIDE + si0*2;
        #pragma unroll
        for (int b = 0; b < 16; ++b) {
            const int e = b >> 1, s = b & 1;
            const float va = ((const float*)&v[b>>2])[b&3];
            const float vb = ((const float*)&v[4 + (b>>2)])[b&3];
            *(unsigned*)(base + e*16*X1_STRIDE + s*128) = pack2(va, vb);
        }
        if (t < 16) lref[t] = ref[((long)(p0 + t))*16 + 15];
    }
    __syncthreads();   // X1 staged AND w1-chunk0 landed (vmcnt0 at barrier)

    // ---- phase 1: 24 chunks, dbuf; accumulate accL/accR[16] ----
    f32x4 accL[16], accR[16];
    #pragma unroll
    for (int j = 0; j < 16; ++j) { accL[j] = (f32x4)0.f; accR[j] = (f32x4)0.f; }

    #pragma unroll
    for (int c = 0; c < 24; ++c) {
        if (c < 23) {   // prefetch next chunk into other buffer
            const char* gsrc = (const char*)w1s + (c + 1)*32768 + dmaOff;
            char* ldst = LDS + WBOFF + ((c + 1) & 1)*32768 + w*1024;
            #pragma unroll
            for (int r = 0; r < 4; ++r)
                gload16(gsrc + r*8192, ldst + r*8192);
        }
        const int e = c / 3, v = c - 3*e;
        const int j = 2*e + (v ? 1 : 0);
        const int khb2 = (v == 2) ? 128 : 0;       // byte offset of k-half in X1 row
        const char* WBc = LDS + WBOFF + (c & 1)*32768;
        const char* xrow = LDS + ln*X1_STRIDE + e*16*X1_STRIDE + khb2 + lh*16;
        #pragma unroll
        for (int kf2 = 0; kf2 < 2; ++kf2) {
            const bf16x8 bx = *(const bf16x8*)(xrow + kf2*64);
            const bf16x8 aL = *(const bf16x8*)(WBc + (aLo ^ (kf2*64)));
            accL[j] = __builtin_amdgcn_mfma_f32_16x16x32_bf16(aL, bx, accL[j], 0, 0, 0);
            const bf16x8 aR = *(const bf16x8*)(WBc + (aRo ^ (kf2*64)));
            accR[j] = __builtin_amdgcn_mfma_f32_16x16x32_bf16(aR, bx, accR[j], 0, 0, 0);
        }
        __syncthreads();   // chunk c reads done; chunk c+1 landed
    }
    #pragma unroll
    for (int r = 0; r < 4; ++r) {
        accL[0][r] += b1[f0*16 + lh*4 + r];
        accR[0][r] += b1[(f0 + 4)*16 + lh*4 + r];
    }

    // ---- issue DMA of w2 chunk 0 (overlaps product VALU burst) ----
    {
        char* ldst = LDS + WBOFF;
        #pragma unroll
        for (int r = 0; r < 2; ++r)
            gload16((const char*)w2s + r*8192 + dmaOff, ldst + r*8192 + w*1024);
    }

    // ---- products in-register (verified R9 tables) ----
    f32x4 prod[16];
    #pragma unroll
    for (int j = 0; j < 16; ++j) prod[j] = (f32x4)0.f;
    if (st == 0) {
        #pragma unroll
        for (int A = 0; A < 16; ++A)
            #pragma unroll
            for (int B = 0; B < 16; ++B) {
                if (TB.gp[A][B] > 0.f)      prod[A ^ B] += accL[A] * accR[B];
                else if (TB.gp[A][B] < 0.f) prod[A ^ B] -= accL[A] * accR[B];
            }
    } else {
        #pragma unroll
        for (int A = 0; A < 16; ++A)
            #pragma unroll
            for (int B = 0; B < 16; ++B) {
                if (TB.jn[A][B] > 0.f)      prod[A & B] += accL[A] * accR[B];
                else if (TB.jn[A][B] < 0.f) prod[A & B] -= accL[A] * accR[B];
            }
        const float rv = lref[ln];
        #pragma unroll
        for (int j = 0; j < 16; ++j) prod[j] *= rv;
    }

    // ---- write prod -> X2 at LDS+0 (X1 dead), 544B rows ----
    {
        const int vX2w = ln*X2_STRIDE + w*32 + lh*8;
        #pragma unroll
        for (int e2 = 0; e2 < 8; ++e2)
            #pragma unroll
            for (int s = 0; s < 2; ++s)
                #pragma unroll
                for (int rp = 0; rp < 4; rp += 2)
                    *(unsigned*)(LDS + vX2w + e2*16*X2_STRIDE + s*256 + rp*2) =
                        pack2(prod[2*e2 + s][rp], prod[2*e2 + s][rp + 1]);
    }
    __syncthreads();   // X2 visible AND w2-chunk0 landed

    // ---- phase 2: 24 chunks (16KB), dbuf; wave handles its st-half ----
    f32x4 acc2[8];
    #pragma unroll
    for (int jj = 0; jj < 8; ++jj) acc2[jj] = (f32x4)0.f;

    const int ch2 = grp*16 + ln;
    const int a2o = ch2*256 + ((lh*16) ^ ((ch2 & 7) << 4));

    #pragma unroll
    for (int d = 0; d < 24; ++d) {
        if (d < 23) {
            const char* gsrc = (const char*)w2s + (d + 1)*16384 + dmaOff;
            char* ldst = LDS + WBOFF + ((d + 1) & 1)*16384 + w*1024;
            #pragma unroll
            for (int r = 0; r < 2; ++r)
                gload16(gsrc + r*8192, ldst + r*8192);
        }
        const int e2 = d / 3, v = d - 3*e2;
        const int j2 = 2*e2 + (v ? 1 : 0);
        if ((j2 >> 3) == st) {
            const int jj = j2 & 7;
            const int khb2 = (v == 2) ? 256 : 0;   // byte offset of k2-half in X2 row
            const char* PBd = LDS + WBOFF + (d & 1)*16384;
            const char* xrow = LDS + ln*X2_STRIDE + e2*16*X2_STRIDE + khb2 + lh*16;
            #pragma unroll
            for (int kf2 = 0; kf2 < 4; ++kf2) {
                const bf16x8 bx = *(const bf16x8*)(xrow + kf2*64);
                const bf16x8 a  = *(const bf16x8*)(PBd + (a2o ^ (kf2*64)));
                acc2[jj] = __builtin_amdgcn_mfma_f32_16x16x32_bf16(a, bx, acc2[jj], 0, 0, 0);
            }
        }
        __syncthreads();
    }
    if (st == 0) {
        #pragma unroll
        for (int r = 0; r < 4; ++r) acc2[0][r] += b2[grp*16 + lh*4 + r];
    }
    __syncthreads();   // X2 reads done; region becomes epilogue buffer

    // ---- epilogue: fp32 [pos][o2*16+j] rows of 4112B -> coalesced stores ----
    {
        const int vEp = ln*EP_STRIDE + grp*1024 + lh*256 + st*32;
        #pragma unroll
        for (int r = 0; r < 4; ++r) {
            *(float4*)(LDS + vEp + r*64) =
                make_float4(acc2[0][r], acc2[1][r], acc2[2][r], acc2[3][r]);
            *(float4*)(LDS + vEp + r*64 + 16) =
                make_float4(acc2[4][r], acc2[5][r], acc2[6][r], acc2[7][r]);
        }
    }
    __syncthreads();
    {
        #pragma unroll
        for (int it = 0; it < 8; ++it) {
            const int idx = it*512 + t;
            const int pos = idx >> 8, off = idx & 255;
            const float4 vv = *(const float4*)(LDS + pos*EP_STRIDE + off*16);
            *(float4*)(out + ((long)(p0 + pos))*1024 + off*4) = vv;
        }
    }
}

// ---------------- fp32 last-resort fallback (verified R3) --------------------
__global__ __launch_bounds__(256, 1) void gb_fused_f32(
    const float* __restrict__ x, const float* __restrict__ ref,
    const float* __restrict__ w1, const float* __restrict__ b1,
    const float* __restrict__ w2, const float* __restrict__ b2,
    float* __restrict__ out)
{
    __shared__ float lds[16384];
    __shared__ float lrefs[8];
    const int t = threadIdx.x;
    const int p0 = blockIdx.x * 8;
    {
        const float4* xg = reinterpret_cast<const float4*>(x) + (size_t)p0 * 256;
        float4* xl = reinterpret_cast<float4*>(lds);
        #pragma unroll
        for (int r = 0; r < 8; ++r) xl[r*256 + t] = xg[r*256 + t];
        if (t < 8) lrefs[t] = ref[(p0 + t)*16 + 15];
    }
    __syncthreads();
    const int c    = t & 127;
    const int half = t >> 7;
    const int ca   = (c < 64) ? c : (c + 64);
    const int cb   = ca + 64;
    float acc[4][2][16];
    #pragma unroll
    for (int q = 0; q < 4; ++q)
        #pragma unroll
        for (int s = 0; s < 2; ++s)
            #pragma unroll
            for (int j = 0; j < 16; ++j) acc[q][s][j] = 0.f;
    for (int i = 0; i < 64; ++i) {
        float wa[9], wb[9];
        #pragma unroll
        for (int r = 0; r < 9; ++r) { wa[r] = w1[(ca*64+i)*9 + r]; wb[r] = w1[(cb*64+i)*9 + r]; }
        #pragma unroll
        for (int q = 0; q < 4; ++q) {
            const float* xv = lds + (half*4 + q)*1024 + i*16;
            float xr[16];
            #pragma unroll
            for (int j4 = 0; j4 < 4; ++j4) {
                const float4 v = *reinterpret_cast<const float4*>(xv + 4*j4);
                xr[4*j4+0]=v.x; xr[4*j4+1]=v.y; xr[4*j4+2]=v.z; xr[4*j4+3]=v.w;
            }
            #pragma unroll
            for (int e = 0; e < 8; ++e) {
                const int ge = GE[e];
                const float xe = xr[2*e], xo = xr[2*e+1];
                acc[q][0][2*e]   += wa[ge]   * xe;
                acc[q][0][2*e+1] += wa[ge+1] * xo;
                acc[q][0][2*e+1] += wa[ge+5] * xe;
                acc[q][1][2*e]   += wb[ge]   * xe;
                acc[q][1][2*e+1] += wb[ge+1] * xo;
                acc[q][1][2*e+1] += wb[ge+5] * xe;
            }
        }
    }
    {
        const float ba = b1[ca], bb = b1[cb];
        #pragma unroll
        for (int q = 0; q < 4; ++q) { acc[q][0][0] += ba; acc[q][1][0] += bb; }
    }
    __syncthreads();
    #pragma unroll
    for (int q = 0; q < 4; ++q) {
        float prod[16];
        #pragma unroll
        for (int j = 0; j < 16; ++j) prod[j] = 0.f;
        if (c < 64) {
            #pragma unroll
            for (int A = 0; A < 16; ++A)
                #pragma unroll
                for (int B = 0; B < 16; ++B)
                    if (TB.gp[A][B] != 0.f)
                        prod[A ^ B] += TB.gp[A][B] * acc[q][0][A] * acc[q][1][B];
        } else {
            #pragma unroll
            for (int A = 0; A < 16; ++A)
                #pragma unroll
                for (int B = 0; B < 16; ++B)
                    if (TB.jn[A][B] != 0.f)
                        prod[A & B] += TB.jn[A][B] * acc[q][0][A] * acc[q][1][B];
            const float rp = lrefs[half*4 + q];
            #pragma unroll
            for (int j = 0; j < 16; ++j) prod[j] *= rp;
        }
        const int pos = half*4 + q;
        #pragma unroll
        for (int j4 = 0; j4 < 4; ++j4)
            *reinterpret_cast<float4*>(&lds[(pos*4 + j4)*512 + c*4]) =
                make_float4(prod[4*j4], prod[4*j4+1], prod[4*j4+2], prod[4*j4+3]);
    }
    __syncthreads();
    const int o    = t & 63;
    const int slot = t >> 6;
    float oacc[2][16];
    #pragma unroll
    for (int e2 = 0; e2 < 2; ++e2)
        #pragma unroll
        for (int j = 0; j < 16; ++j) oacc[e2][j] = 0.f;
    for (int i = 0; i < 128; ++i) {
        float wv[9];
        #pragma unroll
        for (int r = 0; r < 9; ++r) wv[r] = w2[(o*128+i)*9 + r];
        #pragma unroll
        for (int e2 = 0; e2 < 2; ++e2) {
            const int pos = slot*2 + e2;
            float xr[16];
            #pragma unroll
            for (int j4 = 0; j4 < 4; ++j4) {
                const float4 v = *reinterpret_cast<const float4*>(&lds[(pos*4 + j4)*512 + i*4]);
                xr[4*j4+0]=v.x; xr[4*j4+1]=v.y; xr[4*j4+2]=v.z; xr[4*j4+3]=v.w;
            }
            #pragma unroll
            for (int e = 0; e < 8; ++e) {
                const int ge = GE[e];
                oacc[e2][2*e]   += wv[ge]   * xr[2*e];
                oacc[e2][2*e+1] += wv[ge+1] * xr[2*e+1];
                oacc[e2][2*e+1] += wv[ge+5] * xr[2*e];
            }
        }
    }
    {
        const float bo = b2[o];
        #pragma unroll
        for (int e2 = 0; e2 < 2; ++e2) {
            oacc[e2][0] += bo;
            const int pos = p0 + slot*2 + e2;
            float* og = out + (size_t)pos*1024 + o*16;
            #pragma unroll
            for (int j4 = 0; j4 < 4; ++j4)
                *reinterpret_cast<float4*>(og + 4*j4) =
                    make_float4(oacc[e2][4*j4], oacc[e2][4*j4+1],
                                oacc[e2][4*j4+2], oacc[e2][4*j4+3]);
        }
    }
}

extern "C" void kernel_launch(void* const* d_in, const int* in_sizes, int n_in,
                              void* d_out, int out_size, void* d_ws, size_t ws_size,
                              hipStream_t stream)
{
    const float* x  = (const float*)d_in[0];
    const float* rf = (const float*)d_in[1];
    const float* w1 = (const float*)d_in[2];
    const float* b1 = (const float*)d_in[3];
    const float* w2 = (const float*)d_in[4];
    const float* b2 = (const float*)d_in[5];
    float* out = (float*)d_out;

    const size_t need = (size_t)(W1S_ELEMS + W2S_ELEMS) * sizeof(unsigned short);
    if (ws_size >= need) {
        unsigned short* w1s = (unsigned short*)d_ws;
        unsigned short* w2s = w1s + W1S_ELEMS;
        prep_w<<<(W1S_ELEMS + W2S_ELEMS)/256, 256, 0, stream>>>(w1, w2, w1s, w2s);
        gb3<<<1024, 512, 0, stream>>>(x, rf, b1, b2, w1s, w2s, out);
    } else {
        gb_fused_f32<<<2048, 256, 0, stream>>>(x, rf, w1, b1, w2, b2, out);
    }
}